// Round 2
// baseline (260.695 us; speedup 1.0000x reference)
//
#include <hip/hip_runtime.h>
#include <stdint.h>

#define OUT_F   2048
#define IN_BASE 2048
#define N_EMB   64
#define IN_TOT  2176   // 2048 + 128
#define NNZ_W   400000
#define NNZ_B   1024
#define BATCH   8192

typedef __bf16 bf16x8 __attribute__((ext_vector_type(8)));
typedef __bf16 bf16x4 __attribute__((ext_vector_type(4)));
typedef float  floatx16 __attribute__((ext_vector_type(16)));

#define AS1 __attribute__((address_space(1)))
#define AS3 __attribute__((address_space(3)))

// ---------------------------------------------------------------------------
// Kernel 1 (fused): build_x blocks [0, NB_BUILD) + COO scatter blocks after.
// build_x and scatter are independent; fusing overlaps HBM streaming with
// latency-bound atomics.  Scatter uses unsafeAtomicAdd -> global_atomic_add_f32
// (plain atomicAdd(float*) may lower to a CAS loop).
// ---------------------------------------------------------------------------
#define NB_BUILD (BATCH * (IN_TOT / 4) / 256)      // 17408
#define NB_SCAT  ((NNZ_W + NNZ_B + 255) / 256)     // 1567

__global__ void __launch_bounds__(256) prep_kernel(
    const float* __restrict__ x,
    const float* __restrict__ e0v, const int* __restrict__ e0p,
    const float* __restrict__ e1v, const int* __restrict__ e1p,
    __bf16* __restrict__ xb,
    const float* __restrict__ wv, const int* __restrict__ wr,
    const int* __restrict__ wc,
    const float* __restrict__ bv, const int* __restrict__ bi,
    float* __restrict__ Wf, float* __restrict__ bfp)
{
    if (blockIdx.x < NB_BUILD) {
        const int GROUPS = IN_TOT / 4;                 // 544 groups per row
        int gid = blockIdx.x * 256 + threadIdx.x;
        int b = gid / GROUPS;
        int g = gid - b * GROUPS;
        const float* xr = x + (size_t)b * IN_BASE;

        float v[4];
        if (g < IN_BASE / 4) {
            const float4 t = *(const float4*)(xr + g * 4);
            v[0] = t.x; v[1] = t.y; v[2] = t.z; v[3] = t.w;
        } else if (g < (IN_BASE + N_EMB) / 4) {        // embed0: cols 2048..2111
            int j = (g - IN_BASE / 4) * 4;
#pragma unroll
            for (int t = 0; t < 4; t++) v[t] = e0v[j + t] * xr[e0p[j + t]];
        } else {                                       // embed1: cols 2112..2175
            int j = (g - (IN_BASE + N_EMB) / 4) * 4;
#pragma unroll
            for (int t = 0; t < 4; t++) {
                int p = e1p[j + t];
                float base = (p < IN_BASE) ? xr[p]
                                           : e0v[p - IN_BASE] * xr[e0p[p - IN_BASE]];
                v[t] = e1v[j + t] * base;
            }
        }
        bf16x4 o;
        o[0] = (__bf16)v[0]; o[1] = (__bf16)v[1]; o[2] = (__bf16)v[2]; o[3] = (__bf16)v[3];
        *(bf16x4*)(xb + (size_t)b * IN_TOT + g * 4) = o;
    } else {
        int i = (blockIdx.x - NB_BUILD) * 256 + threadIdx.x;
        if (i < NNZ_W) {
            unsafeAtomicAdd(Wf + (size_t)wr[i] * IN_TOT + wc[i], wv[i]);
        } else if (i < NNZ_W + NNZ_B) {
            int j = i - NNZ_W;
            unsafeAtomicAdd(bfp + bi[j], bv[j]);
        }
    }
}

// ---------------------------------------------------------------------------
// Kernel 2: W fp32 -> bf16
// ---------------------------------------------------------------------------
__global__ void __launch_bounds__(256) w_to_bf16_kernel(
    const float* __restrict__ Wf, __bf16* __restrict__ Wb)
{
    int e = (blockIdx.x * 256 + threadIdx.x) * 4;
    const float4 t = *(const float4*)(Wf + e);
    bf16x4 o;
    o[0] = (__bf16)t.x; o[1] = (__bf16)t.y; o[2] = (__bf16)t.z; o[3] = (__bf16)t.w;
    *(bf16x4*)(Wb + e) = o;
}

// ---------------------------------------------------------------------------
// Kernel 3: GEMM  C[M,N] = A[M,K] * W[N,K]^T + bias   (K-major, "NT")
//
// 256x256 tile, 8 waves (2M x 4N), wave tile 128x64 as quadrants of 64x32,
// mfma_f32_32x32x16_bf16, BK=64, double-buffered LDS (128 KiB), 8-phase
// schedule with COUNTED vmcnt (T3+T4), setprio around MFMA clusters (T5),
// 16B-chunk XOR swizzle on LDS (T2, realized on global side of gl_lds).
//
// Phase->quadrant map per K-tile: (m,n) = (0,0),(0,1),(1,1),(1,0).
// Region-free schedule (verified by outstanding-op counting): for the tile in
// a buffer, A-half0 free after phase 2, B-half1 after phase 3, A-half1/B-half0
// after phase 4.  Staging issue slots (1 matrix-half = 2 gl_lds per phase):
//   ph1: t(2i+1) A-h1 -> buf1     ph5: t(2i+2) A-h1 -> buf0
//   ph2: t(2i+1) B-h0 -> buf1     ph6: t(2i+2) B-h0 -> buf0
//   ph3: t(2i+2) A-h0 -> buf0     ph7: t(2i+3) A-h0 -> buf1
//   ph4: t(2i+2) B-h1 -> buf0     ph8: t(2i+3) B-h1 -> buf1
// At ph4's VMW(4): 12 outstanding, 8 oldest (= all of tile 2i+1) forced to
// land before the barrier; ph8's VMW(4) covers tile 2i+2.  Last iteration
// peeled: vmcnt(0) at ph4.  Raw s_barrier only — __syncthreads would drain
// vmcnt and collapse the pipeline.
// ---------------------------------------------------------------------------
#define BM 256
#define BN 256
#define BK 64
#define NKT (IN_TOT / BK)   // 34 K-tiles, 17 iterations of 2
static_assert(NKT % 2 == 0, "pipeline consumes K-tiles in pairs");

#define CFENCE asm volatile("" ::: "memory")
#define BAR do { CFENCE; __builtin_amdgcn_s_barrier(); CFENCE; } while (0)
#define VMW(n) asm volatile("s_waitcnt vmcnt(" #n ")" ::: "memory")
#define NOPS do {} while (0)

// stage one matrix-half (128 rows x 64 k) of K-tile `tile` into buffer `buf`
#define STAGE(G, SBC, buf, tile, half) do {                                     \
    const __bf16* _s = (G) + (size_t)((half) * 128) * IN_TOT + (tile) * 64;     \
    char* _d = (SBC) + (buf) * 32768 + (half) * 16384 + tid * 16;               \
    __builtin_amdgcn_global_load_lds((AS1 void*)(uintptr_t)_s,                  \
                                     (AS3 void*)_d, 16, 0, 0);                  \
    __builtin_amdgcn_global_load_lds((AS1 void*)(uintptr_t)(_s + (size_t)64 * IN_TOT), \
                                     (AS3 void*)(_d + 8192), 16, 0, 0);         \
} while (0)

// one phase: 12 ds_read_b128 -> stage issue -> [wait] -> barrier -> 8 MFMA -> barrier
#define PHASE(buf, m, n, STG, WT) do {                                          \
    const __bf16* _pA = sA + (buf) * 16384;                                     \
    const __bf16* _pB = sB + (buf) * 16384;                                     \
    bf16x8 _af[2][4], _bv[4];                                                   \
    _Pragma("unroll") for (int ks = 0; ks < 4; ks++) {                          \
        const int kc = ks * 2 + khalf;                                          \
        _Pragma("unroll") for (int mi = 0; mi < 2; mi++) {                      \
            const int r = (m) * 128 + wm * 64 + mi * 32 + l32;                  \
            _af[mi][ks] = *(const bf16x8*)(_pA + r * 64 + ((kc ^ (r & 7)) * 8));\
        }                                                                       \
        const int rb = (n) * 128 + wn * 32 + l32;                               \
        _bv[ks] = *(const bf16x8*)(_pB + rb * 64 + ((kc ^ (rb & 7)) * 8));      \
    }                                                                           \
    STG;                                                                        \
    WT;                                                                         \
    BAR;                                                                        \
    __builtin_amdgcn_s_setprio(1);                                              \
    _Pragma("unroll") for (int mi = 0; mi < 2; mi++)                            \
        _Pragma("unroll") for (int ks = 0; ks < 4; ks++)                        \
            acc[m][mi][n] = __builtin_amdgcn_mfma_f32_32x32x16_bf16(            \
                _af[mi][ks], _bv[ks], acc[m][mi][n], 0, 0, 0);                  \
    __builtin_amdgcn_s_setprio(0);                                              \
    BAR;                                                                        \
} while (0)

__global__ void __launch_bounds__(512, 2) gemm_kernel(
    const __bf16* __restrict__ A,   // [BATCH][IN_TOT]
    const __bf16* __restrict__ W,   // [OUT_F][IN_TOT]
    const float*  __restrict__ bias,
    float* __restrict__ C)          // [BATCH][OUT_F]
{
    __shared__ __align__(16) __bf16 sA[2 * 256 * 64];   // 64 KiB (2 bufs)
    __shared__ __align__(16) __bf16 sB[2 * 256 * 64];   // 64 KiB

    const int tid   = threadIdx.x;
    const int bm    = blockIdx.x;    // M tile (32)
    const int bn    = blockIdx.y;    // N tile (8)
    const int wave  = tid >> 6;
    const int lane  = tid & 63;
    const int wm    = wave >> 2;     // 0..1
    const int wn    = wave & 3;      // 0..3
    const int l32   = lane & 31;
    const int khalf = lane >> 5;

    floatx16 acc[2][2][2] = {};      // [m quadrant][mi (32-row)][n quadrant]

    // staging: thread t -> row = t>>3 (64 rows/load, x2 at +64), slot = t&7.
    // slot s of row r holds global chunk s ^ (r&7) => fetch chunk (t&7)^((t>>3)&7)
    const int srow   = tid >> 3;
    const int kchunk = ((tid & 7) ^ ((tid >> 3) & 7)) * 8;
    const __bf16* Ag = A + (size_t)(bm * BM + srow) * IN_TOT + kchunk;
    const __bf16* Wg = W + (size_t)(bn * BN + srow) * IN_TOT + kchunk;
    char* sAc = (char*)sA;
    char* sBc = (char*)sB;

    // prologue: tile0 fully, tile1 A-h0 + B-h1  (12 loads; wait until only
    // tile1's 4 remain outstanding)
    STAGE(Ag, sAc, 0, 0, 0);
    STAGE(Ag, sAc, 0, 0, 1);
    STAGE(Wg, sBc, 0, 0, 0);
    STAGE(Wg, sBc, 0, 0, 1);
    STAGE(Ag, sAc, 1, 1, 0);
    STAGE(Wg, sBc, 1, 1, 1);
    VMW(4);
    BAR;

#pragma unroll 1
    for (int i = 0; i < NKT / 2 - 1; ++i) {
        const int t1 = 2 * i + 1, t2 = 2 * i + 2, t3 = 2 * i + 3;
        PHASE(0, 0, 0, STAGE(Ag, sAc, 1, t1, 1), NOPS);
        PHASE(0, 0, 1, STAGE(Wg, sBc, 1, t1, 0), NOPS);
        PHASE(0, 1, 1, STAGE(Ag, sAc, 0, t2, 0), NOPS);
        PHASE(0, 1, 0, STAGE(Wg, sBc, 0, t2, 1), VMW(4));
        PHASE(1, 0, 0, STAGE(Ag, sAc, 0, t2, 1), NOPS);
        PHASE(1, 0, 1, STAGE(Wg, sBc, 0, t2, 0), NOPS);
        PHASE(1, 1, 1, STAGE(Ag, sAc, 1, t3, 0), NOPS);
        PHASE(1, 1, 0, STAGE(Wg, sBc, 1, t3, 1), VMW(4));
    }
    // peeled last iteration: tiles 32,33 — only tile-33 leftovers staged
    PHASE(0, 0, 0, STAGE(Ag, sAc, 1, NKT - 1, 1), NOPS);
    PHASE(0, 0, 1, STAGE(Wg, sBc, 1, NKT - 1, 0), NOPS);
    PHASE(0, 1, 1, NOPS, NOPS);
    PHASE(0, 1, 0, NOPS, VMW(0));
    PHASE(1, 0, 0, NOPS, NOPS);
    PHASE(1, 0, 1, NOPS, NOPS);
    PHASE(1, 1, 1, NOPS, NOPS);
    PHASE(1, 1, 0, NOPS, NOPS);

    // epilogue: C/D col = lane&31, row = (reg&3) + 8*(reg>>2) + 4*khalf  [verified]
#pragma unroll
    for (int m = 0; m < 2; m++)
#pragma unroll
    for (int mi = 0; mi < 2; mi++)
#pragma unroll
    for (int n = 0; n < 2; n++) {
        const int colg = bn * BN + n * 128 + wn * 32 + l32;
        const float bvv = bias[colg];
        const int rowb = bm * BM + m * 128 + wm * 64 + mi * 32 + 4 * khalf;
#pragma unroll
        for (int reg = 0; reg < 16; reg++) {
            const int rowg = rowb + (reg & 3) + 8 * (reg >> 2);
            C[(size_t)rowg * OUT_F + colg] = acc[m][mi][n][reg] + bvv;
        }
    }
}

// ---------------------------------------------------------------------------
// Launch
// ---------------------------------------------------------------------------
extern "C" void kernel_launch(void* const* d_in, const int* in_sizes, int n_in,
                              void* d_out, int out_size, void* d_ws, size_t ws_size,
                              hipStream_t stream) {
    const float* x      = (const float*)d_in[0];
    const float* w_vals = (const float*)d_in[1];
    const int*   w_rows = (const int*)  d_in[2];
    const int*   w_cols = (const int*)  d_in[3];
    const float* b_vals = (const float*)d_in[4];
    const int*   b_idx  = (const int*)  d_in[5];
    const float* e0v    = (const float*)d_in[6];
    const int*   e0p    = (const int*)  d_in[7];
    const float* e1v    = (const float*)d_in[8];
    const int*   e1p    = (const int*)  d_in[9];
    float* out = (float*)d_out;

    // workspace layout: Wf fp32 | bias fp32 (contiguous for single memset) | Wb | xb
    char* ws = (char*)d_ws;
    const size_t W_F32_BYTES  = (size_t)OUT_F * IN_TOT * 4;   // 17,825,792
    const size_t B_F32_BYTES  = (size_t)OUT_F * 4;            //      8,192
    const size_t W_BF16_BYTES = (size_t)OUT_F * IN_TOT * 2;   //  8,912,896
    float*  Wf = (float*)ws;
    float*  bfp = (float*)(ws + W_F32_BYTES);
    __bf16* Wb = (__bf16*)(ws + W_F32_BYTES + B_F32_BYTES);
    __bf16* xb = (__bf16*)(ws + W_F32_BYTES + B_F32_BYTES + W_BF16_BYTES);

    // single memset covers Wf + bias
    hipMemsetAsync(Wf, 0, W_F32_BYTES + B_F32_BYTES, stream);

    prep_kernel<<<NB_BUILD + NB_SCAT, 256, 0, stream>>>(
        x, e0v, e0p, e1v, e1p, xb,
        w_vals, w_rows, w_cols, b_vals, b_idx, Wf, bfp);

    w_to_bf16_kernel<<<((size_t)OUT_F * IN_TOT / 4) / 256, 256, 0, stream>>>(Wf, Wb);

    dim3 grid(BATCH / BM, OUT_F / BN);
    gemm_kernel<<<grid, 512, 0, stream>>>(xb, Wb, bfp, out);
}

// Round 3
// 231.770 us; speedup vs baseline: 1.1248x; 1.1248x over previous
//
#include <hip/hip_runtime.h>
#include <stdint.h>

#define OUT_F   2048
#define IN_BASE 2048
#define N_EMB   64
#define IN_TOT  2176   // 2048 + 128
#define NNZ_W   400000
#define NNZ_B   1024
#define BATCH   8192

typedef __bf16 bf16x8 __attribute__((ext_vector_type(8)));
typedef __bf16 bf16x4 __attribute__((ext_vector_type(4)));
typedef float  floatx16 __attribute__((ext_vector_type(16)));

#define AS1 __attribute__((address_space(1)))
#define AS3 __attribute__((address_space(3)))

// ---------------------------------------------------------------------------
// Kernel 1 (fused): build_x blocks [0, NB_BUILD) + COO scatter blocks after.
// ---------------------------------------------------------------------------
#define NB_BUILD (BATCH * (IN_TOT / 4) / 256)      // 17408
#define NB_SCAT  ((NNZ_W + NNZ_B + 255) / 256)     // 1567

__global__ void __launch_bounds__(256) prep_kernel(
    const float* __restrict__ x,
    const float* __restrict__ e0v, const int* __restrict__ e0p,
    const float* __restrict__ e1v, const int* __restrict__ e1p,
    __bf16* __restrict__ xb,
    const float* __restrict__ wv, const int* __restrict__ wr,
    const int* __restrict__ wc,
    const float* __restrict__ bv, const int* __restrict__ bi,
    float* __restrict__ Wf, float* __restrict__ bfp)
{
    if (blockIdx.x < NB_BUILD) {
        const int GROUPS = IN_TOT / 4;                 // 544 groups per row
        int gid = blockIdx.x * 256 + threadIdx.x;
        int b = gid / GROUPS;
        int g = gid - b * GROUPS;
        const float* xr = x + (size_t)b * IN_BASE;

        float v[4];
        if (g < IN_BASE / 4) {
            const float4 t = *(const float4*)(xr + g * 4);
            v[0] = t.x; v[1] = t.y; v[2] = t.z; v[3] = t.w;
        } else if (g < (IN_BASE + N_EMB) / 4) {        // embed0: cols 2048..2111
            int j = (g - IN_BASE / 4) * 4;
#pragma unroll
            for (int t = 0; t < 4; t++) v[t] = e0v[j + t] * xr[e0p[j + t]];
        } else {                                       // embed1: cols 2112..2175
            int j = (g - (IN_BASE + N_EMB) / 4) * 4;
#pragma unroll
            for (int t = 0; t < 4; t++) {
                int p = e1p[j + t];
                float base = (p < IN_BASE) ? xr[p]
                                           : e0v[p - IN_BASE] * xr[e0p[p - IN_BASE]];
                v[t] = e1v[j + t] * base;
            }
        }
        bf16x4 o;
        o[0] = (__bf16)v[0]; o[1] = (__bf16)v[1]; o[2] = (__bf16)v[2]; o[3] = (__bf16)v[3];
        *(bf16x4*)(xb + (size_t)b * IN_TOT + g * 4) = o;
    } else {
        int i = (blockIdx.x - NB_BUILD) * 256 + threadIdx.x;
        if (i < NNZ_W) {
            unsafeAtomicAdd(Wf + (size_t)wr[i] * IN_TOT + wc[i], wv[i]);
        } else if (i < NNZ_W + NNZ_B) {
            int j = i - NNZ_W;
            unsafeAtomicAdd(bfp + bi[j], bv[j]);
        }
    }
}

// ---------------------------------------------------------------------------
// Kernel 2: W fp32 -> bf16
// ---------------------------------------------------------------------------
__global__ void __launch_bounds__(256) w_to_bf16_kernel(
    const float* __restrict__ Wf, __bf16* __restrict__ Wb)
{
    int e = (blockIdx.x * 256 + threadIdx.x) * 4;
    const float4 t = *(const float4*)(Wf + e);
    bf16x4 o;
    o[0] = (__bf16)t.x; o[1] = (__bf16)t.y; o[2] = (__bf16)t.z; o[3] = (__bf16)t.w;
    *(bf16x4*)(Wb + e) = o;
}

// ---------------------------------------------------------------------------
// Kernel 3: GEMM  C[M,N] = A[M,K] * W[N,K]^T + bias   (K-major, "NT")
//
// 256x256 tile, 8 waves (2M x 4N), wave tile 128x64 as quadrants of 64x32,
// mfma_f32_32x32x16_bf16, BK=64, double-buffered LDS (128 KiB), 4 phases per
// K-tile with COUNTED vmcnt (T3+T4), setprio around MFMA clusters (T5),
// 16B-chunk XOR swizzle (T2, realized on global side of gl_lds).
//
// REG-CACHED fragments (round-2 lesson): phase ring (0,0),(0,1),(1,1),(1,0);
// ph1 reads A(m0)+B(n0) [12x ds_read_b128], ph2 reads B(n1) [4], ph3 reads
// A(m1) [8, overwrites A regs], ph4 reads NOTHING (B(n0) held since ph1).
// 24 reads / 32 MFMA per wave per K-tile (was 48) — LDS read cycles/K-tile
// ~2300 vs MFMA-pipe 2048, removing the 2x LDS-read bottleneck measured in
// round 2 (MfmaUtil 25%, 13.4M bank-conflict cycles).
//
// Staging issue slots (1 matrix-half = 2 gl_lds per phase) and waits are
// UNCHANGED from the verified round-2 schedule:
//   ph1: t(2i+1) A-h1 -> buf1     ph5: t(2i+2) A-h1 -> buf0
//   ph2: t(2i+1) B-h0 -> buf1     ph6: t(2i+2) B-h0 -> buf0
//   ph3: t(2i+2) A-h0 -> buf0     ph7: t(2i+3) A-h0 -> buf1
//   ph4: t(2i+2) B-h1 -> buf0     ph8: t(2i+3) B-h1 -> buf1
// VMW(4) at ph4 forces the 8 oldest (= all of tile 2i+1) to land; ph8's
// VMW(4) covers tile 2i+2.  Writes to a region are always issued after the
// barrier closing that region's last reader phase (caching only frees
// regions EARLIER).  Peel: vmcnt(0) at ph4.  Raw s_barrier only.
// ---------------------------------------------------------------------------
#define BM 256
#define BN 256
#define BK 64
#define NKT (IN_TOT / BK)   // 34 K-tiles, 17 iterations of 2
static_assert(NKT % 2 == 0, "pipeline consumes K-tiles in pairs");

#define CFENCE asm volatile("" ::: "memory")
#define BAR do { CFENCE; __builtin_amdgcn_s_barrier(); CFENCE; } while (0)
#define VMW(n) asm volatile("s_waitcnt vmcnt(" #n ")" ::: "memory")
#define NOPS do {} while (0)

// stage one matrix-half (128 rows x 64 k) of K-tile `tile` into buffer `buf`
#define STAGE(G, SBC, buf, tile, half) do {                                     \
    const __bf16* _s = (G) + (size_t)((half) * 128) * IN_TOT + (tile) * 64;     \
    char* _d = (SBC) + (buf) * 32768 + (half) * 16384 + tid * 16;               \
    __builtin_amdgcn_global_load_lds((AS1 void*)(uintptr_t)_s,                  \
                                     (AS3 void*)_d, 16, 0, 0);                  \
    __builtin_amdgcn_global_load_lds((AS1 void*)(uintptr_t)(_s + (size_t)64 * IN_TOT), \
                                     (AS3 void*)(_d + 8192), 16, 0, 0);         \
} while (0)

// read the 8 A fragments of m-quadrant mq into a[]
#define RD_A(pA, mq) do {                                                       \
    _Pragma("unroll") for (int ks = 0; ks < 4; ks++) {                          \
        const int kc = ks * 2 + khalf;                                          \
        _Pragma("unroll") for (int mi = 0; mi < 2; mi++) {                      \
            const int r = (mq) * 128 + wm * 64 + mi * 32 + l32;                 \
            a[mi * 4 + ks] = *(const bf16x8*)((pA) + r * 64 + ((kc ^ (r & 7)) * 8)); \
        }                                                                       \
    }                                                                           \
} while (0)

// read the 4 B fragments of n-quadrant nq into barr[]
#define RD_B(pB, nq, barr) do {                                                 \
    _Pragma("unroll") for (int ks = 0; ks < 4; ks++) {                          \
        const int kc = ks * 2 + khalf;                                          \
        const int rb = (nq) * 128 + wn * 32 + l32;                              \
        barr[ks] = *(const bf16x8*)((pB) + rb * 64 + ((kc ^ (rb & 7)) * 8));    \
    }                                                                           \
} while (0)

// barrier -> prio -> 8 MFMA (quadrant mq x nq from a[], barr[]) -> barrier
#define MMPH(mq, nq, barr) do {                                                 \
    BAR;                                                                        \
    __builtin_amdgcn_s_setprio(1);                                              \
    _Pragma("unroll") for (int mi = 0; mi < 2; mi++)                            \
        _Pragma("unroll") for (int ks = 0; ks < 4; ks++)                        \
            acc[mq][mi][nq] = __builtin_amdgcn_mfma_f32_32x32x16_bf16(          \
                a[mi * 4 + ks], barr[ks], acc[mq][mi][nq], 0, 0, 0);            \
    __builtin_amdgcn_s_setprio(0);                                              \
    BAR;                                                                        \
} while (0)

// one K-tile = 4 phases; STGn issued in phase n, W4 waited in phase 4
#define KTILE(buf, STG1, STG2, STG3, STG4, W4) do {                             \
    const __bf16* _pA = sA + (buf) * 16384;                                     \
    const __bf16* _pB = sB + (buf) * 16384;                                     \
    RD_A(_pA, 0); RD_B(_pB, 0, b0);                                             \
    STG1;              MMPH(0, 0, b0);                                          \
    RD_B(_pB, 1, b1);                                                           \
    STG2;              MMPH(0, 1, b1);                                          \
    RD_A(_pA, 1);                                                               \
    STG3;              MMPH(1, 1, b1);                                          \
    STG4; W4;          MMPH(1, 0, b0);                                          \
} while (0)

__global__ void __launch_bounds__(512, 2) gemm_kernel(
    const __bf16* __restrict__ A,   // [BATCH][IN_TOT]
    const __bf16* __restrict__ W,   // [OUT_F][IN_TOT]
    const float*  __restrict__ bias,
    float* __restrict__ C)          // [BATCH][OUT_F]
{
    __shared__ __align__(16) __bf16 sA[2 * 256 * 64];   // 64 KiB (2 bufs)
    __shared__ __align__(16) __bf16 sB[2 * 256 * 64];   // 64 KiB

    const int tid   = threadIdx.x;
    const int bm    = blockIdx.x;    // M tile (32)
    const int bn    = blockIdx.y;    // N tile (8)
    const int wave  = tid >> 6;
    const int lane  = tid & 63;
    const int wm    = wave >> 2;     // 0..1
    const int wn    = wave & 3;      // 0..3
    const int l32   = lane & 31;
    const int khalf = lane >> 5;

    floatx16 acc[2][2][2] = {};      // [m quadrant][mi (32-row)][n quadrant]
    bf16x8 a[8];                     // A-frag cache: [mi][ks], current m-quadrant
    bf16x8 b0[4], b1[4];             // B-frag caches for n-quadrant 0 / 1

    // staging: thread t -> row = t>>3 (64 rows/load, x2 at +64), slot = t&7.
    // slot s of row r holds global chunk s ^ (r&7) => fetch chunk (t&7)^((t>>3)&7)
    const int srow   = tid >> 3;
    const int kchunk = ((tid & 7) ^ ((tid >> 3) & 7)) * 8;
    const __bf16* Ag = A + (size_t)(bm * BM + srow) * IN_TOT + kchunk;
    const __bf16* Wg = W + (size_t)(bn * BN + srow) * IN_TOT + kchunk;
    char* sAc = (char*)sA;
    char* sBc = (char*)sB;

    // prologue: tile0 fully, tile1 A-h0 + B-h1  (12 loads; wait until only
    // tile1's 4 remain outstanding)
    STAGE(Ag, sAc, 0, 0, 0);
    STAGE(Ag, sAc, 0, 0, 1);
    STAGE(Wg, sBc, 0, 0, 0);
    STAGE(Wg, sBc, 0, 0, 1);
    STAGE(Ag, sAc, 1, 1, 0);
    STAGE(Wg, sBc, 1, 1, 1);
    VMW(4);
    BAR;

#pragma unroll 1
    for (int i = 0; i < NKT / 2 - 1; ++i) {
        const int t1 = 2 * i + 1, t2 = 2 * i + 2, t3 = 2 * i + 3;
        KTILE(0, STAGE(Ag, sAc, 1, t1, 1), STAGE(Wg, sBc, 1, t1, 0),
                 STAGE(Ag, sAc, 0, t2, 0), STAGE(Wg, sBc, 0, t2, 1), VMW(4));
        KTILE(1, STAGE(Ag, sAc, 0, t2, 1), STAGE(Wg, sBc, 0, t2, 0),
                 STAGE(Ag, sAc, 1, t3, 0), STAGE(Wg, sBc, 1, t3, 1), VMW(4));
    }
    // peeled last iteration: tiles 32,33 — only tile-33 leftovers staged
    KTILE(0, STAGE(Ag, sAc, 1, NKT - 1, 1), STAGE(Wg, sBc, 1, NKT - 1, 0),
             NOPS, NOPS, VMW(0));
    KTILE(1, NOPS, NOPS, NOPS, NOPS, NOPS);

    // epilogue: C/D col = lane&31, row = (reg&3) + 8*(reg>>2) + 4*khalf  [verified]
#pragma unroll
    for (int m = 0; m < 2; m++)
#pragma unroll
    for (int mi = 0; mi < 2; mi++)
#pragma unroll
    for (int n = 0; n < 2; n++) {
        const int colg = bn * BN + n * 128 + wn * 32 + l32;
        const float bvv = bias[colg];
        const int rowb = bm * BM + m * 128 + wm * 64 + mi * 32 + 4 * khalf;
#pragma unroll
        for (int reg = 0; reg < 16; reg++) {
            const int rowg = rowb + (reg & 3) + 8 * (reg >> 2);
            C[(size_t)rowg * OUT_F + colg] = acc[m][mi][n][reg] + bvv;
        }
    }
}

// ---------------------------------------------------------------------------
// Launch
// ---------------------------------------------------------------------------
extern "C" void kernel_launch(void* const* d_in, const int* in_sizes, int n_in,
                              void* d_out, int out_size, void* d_ws, size_t ws_size,
                              hipStream_t stream) {
    const float* x      = (const float*)d_in[0];
    const float* w_vals = (const float*)d_in[1];
    const int*   w_rows = (const int*)  d_in[2];
    const int*   w_cols = (const int*)  d_in[3];
    const float* b_vals = (const float*)d_in[4];
    const int*   b_idx  = (const int*)  d_in[5];
    const float* e0v    = (const float*)d_in[6];
    const int*   e0p    = (const int*)  d_in[7];
    const float* e1v    = (const float*)d_in[8];
    const int*   e1p    = (const int*)  d_in[9];
    float* out = (float*)d_out;

    // workspace layout: Wf fp32 | bias fp32 (contiguous for single memset) | Wb | xb
    char* ws = (char*)d_ws;
    const size_t W_F32_BYTES  = (size_t)OUT_F * IN_TOT * 4;   // 17,825,792
    const size_t B_F32_BYTES  = (size_t)OUT_F * 4;            //      8,192
    const size_t W_BF16_BYTES = (size_t)OUT_F * IN_TOT * 2;   //  8,912,896
    float*  Wf = (float*)ws;
    float*  bfp = (float*)(ws + W_F32_BYTES);
    __bf16* Wb = (__bf16*)(ws + W_F32_BYTES + B_F32_BYTES);
    __bf16* xb = (__bf16*)(ws + W_F32_BYTES + B_F32_BYTES + W_BF16_BYTES);

    // single memset covers Wf + bias
    hipMemsetAsync(Wf, 0, W_F32_BYTES + B_F32_BYTES, stream);

    prep_kernel<<<NB_BUILD + NB_SCAT, 256, 0, stream>>>(
        x, e0v, e0p, e1v, e1p, xb,
        w_vals, w_rows, w_cols, b_vals, b_idx, Wf, bfp);

    w_to_bf16_kernel<<<((size_t)OUT_F * IN_TOT / 4) / 256, 256, 0, stream>>>(Wf, Wb);

    dim3 grid(BATCH / BM, OUT_F / BN);
    gemm_kernel<<<grid, 512, 0, stream>>>(xb, Wb, bfp, out);
}

// Round 4
// 220.105 us; speedup vs baseline: 1.1844x; 1.0530x over previous
//
#include <hip/hip_runtime.h>
#include <stdint.h>

#define OUT_F   2048
#define IN_BASE 2048
#define N_EMB   64
#define IN_TOT  2176   // 2048 + 128
#define NNZ_W   400000
#define NNZ_B   1024
#define BATCH   8192

typedef __bf16 bf16x8 __attribute__((ext_vector_type(8)));
typedef __bf16 bf16x4 __attribute__((ext_vector_type(4)));
typedef float  floatx16 __attribute__((ext_vector_type(16)));

#define AS1 __attribute__((address_space(1)))
#define AS3 __attribute__((address_space(3)))

// ---------------------------------------------------------------------------
// Kernel 1 (fused): build_x (one block per row, no int division) + COO
// scatter directly into bf16 W via global_atomic_pk_add_bf16 (sums duplicate
// nnz in place; fp32 W buffer + convert kernel deleted).
// ---------------------------------------------------------------------------
#define NB_BUILD BATCH                             // 8192: one row per block
#define NB_SCAT  ((NNZ_W + NNZ_B + 255) / 256)     // 1567

__global__ void __launch_bounds__(256) prep_kernel(
    const float* __restrict__ x,
    const float* __restrict__ e0v, const int* __restrict__ e0p,
    const float* __restrict__ e1v, const int* __restrict__ e1p,
    __bf16* __restrict__ xb,
    const float* __restrict__ wv, const int* __restrict__ wr,
    const int* __restrict__ wc,
    const float* __restrict__ bv, const int* __restrict__ bi,
    __bf16* __restrict__ Wb, float* __restrict__ bfp)
{
    const int tid = threadIdx.x;
    if (blockIdx.x < NB_BUILD) {
        const int b = blockIdx.x;
        const float* xr = x + (size_t)b * IN_BASE;
        __bf16* xo = xb + (size_t)b * IN_TOT;

        // cols 0..2047: straight cast, 2 passes x 256 threads x 4 elems
#pragma unroll
        for (int pass = 0; pass < 2; pass++) {
            const int g = pass * 256 + tid;            // group 0..511
            const float4 t = *(const float4*)(xr + g * 4);
            bf16x4 o;
            o[0] = (__bf16)t.x; o[1] = (__bf16)t.y;
            o[2] = (__bf16)t.z; o[3] = (__bf16)t.w;
            *(bf16x4*)(xo + g * 4) = o;
        }
        // groups 512..543 (cols 2048..2175): embeds, threads 0..31 only
        if (tid < 32) {
            const int g = 512 + tid;
            float v[4];
            if (g < 528) {                             // embed0: cols 2048..2111
                const int j = (g - 512) * 4;
#pragma unroll
                for (int t = 0; t < 4; t++) v[t] = e0v[j + t] * xr[e0p[j + t]];
            } else {                                   // embed1: cols 2112..2175
                const int j = (g - 528) * 4;
#pragma unroll
                for (int t = 0; t < 4; t++) {
                    const int p = e1p[j + t];
                    const float base = (p < IN_BASE)
                        ? xr[p]
                        : e0v[p - IN_BASE] * xr[e0p[p - IN_BASE]];
                    v[t] = e1v[j + t] * base;
                }
            }
            bf16x4 o;
            o[0] = (__bf16)v[0]; o[1] = (__bf16)v[1];
            o[2] = (__bf16)v[2]; o[3] = (__bf16)v[3];
            *(bf16x4*)(xo + g * 4) = o;
        }
    } else {
        const int i = (blockIdx.x - NB_BUILD) * 256 + tid;
        if (i < NNZ_W) {
            const int r = wr[i], c = wc[i];
            const size_t idx = (size_t)r * IN_TOT + c;
            // pack bf16 value into the correct half of the aligned dword;
            // other half adds +0.0 (no-op).  pk-add is atomic on the dword,
            // so duplicate nnz (same or neighboring slot) sum correctly.
            const __bf16 h = (__bf16)wv[i];
            const unsigned short hb = __builtin_bit_cast(unsigned short, h);
            const unsigned int data = (idx & 1) ? ((unsigned int)hb << 16)
                                                : (unsigned int)hb;
            const uint64_t addr = (uint64_t)(uintptr_t)(Wb + (idx & ~(size_t)1));
            asm volatile("global_atomic_pk_add_bf16 %0, %1, off"
                         :: "v"(addr), "v"(data) : "memory");
        } else if (i < NNZ_W + NNZ_B) {
            const int j = i - NNZ_W;
            unsafeAtomicAdd(bfp + bi[j], bv[j]);
        }
        // drain asm atomics before wave exit (EOP-fence insurance)
        asm volatile("s_waitcnt vmcnt(0)" ::: "memory");
    }
}

// ---------------------------------------------------------------------------
// Kernel 2: GEMM  C[M,N] = A[M,K] * W[N,K]^T + bias   (K-major, "NT")
//
// 256x256 tile, 8 waves (2M x 4N), wave tile 128x64 as quadrants of 64x32,
// mfma_f32_32x32x16_bf16, BK=64, double-buffered LDS (128 KiB), 4 phases per
// K-tile with COUNTED vmcnt (T3+T4), setprio around MFMA clusters (T5),
// 16B-chunk XOR swizzle (T2, realized on global side of gl_lds).
//
// REG-CACHED fragments: ph1 reads A(m0)+B(n0) [12x ds_read_b128], ph2 reads
// B(n1) [4], ph3 reads A(m1) [8], ph4 reads nothing.  24 reads / 32 MFMA per
// wave per K-tile.  Measured model (round 3): per K-tile/block LDS drain
// 1536+768conflict cy + MFMA 2048 cy + barriers ~ 5661 cy measured — the
// lockstep structure is ~serial LDS+MFMA, same as the verified m201 template.
//
// Staging slots and waits (verified round-2/3 schedule):
//   ph1: t(2i+1) A-h1 -> buf1     ph5: t(2i+2) A-h1 -> buf0
//   ph2: t(2i+1) B-h0 -> buf1     ph6: t(2i+2) B-h0 -> buf0
//   ph3: t(2i+2) A-h0 -> buf0     ph7: t(2i+3) A-h0 -> buf1
//   ph4: t(2i+2) B-h1 -> buf0     ph8: t(2i+3) B-h1 -> buf1
// VMW(4) at ph4/ph8 forces the next tile's 8 loads to land; peel: vmcnt(0).
// Raw s_barrier only — __syncthreads would drain vmcnt.
// ---------------------------------------------------------------------------
#define BM 256
#define BN 256
#define BK 64
#define NKT (IN_TOT / BK)   // 34 K-tiles, 17 iterations of 2
static_assert(NKT % 2 == 0, "pipeline consumes K-tiles in pairs");

#define CFENCE asm volatile("" ::: "memory")
#define BAR do { CFENCE; __builtin_amdgcn_s_barrier(); CFENCE; } while (0)
#define VMW(n) asm volatile("s_waitcnt vmcnt(" #n ")" ::: "memory")
#define NOPS do {} while (0)

// stage one matrix-half (128 rows x 64 k) of K-tile `tile` into buffer `buf`
#define STAGE(G, SBC, buf, tile, half) do {                                     \
    const __bf16* _s = (G) + (size_t)((half) * 128) * IN_TOT + (tile) * 64;     \
    char* _d = (SBC) + (buf) * 32768 + (half) * 16384 + tid * 16;               \
    __builtin_amdgcn_global_load_lds((AS1 void*)(uintptr_t)_s,                  \
                                     (AS3 void*)_d, 16, 0, 0);                  \
    __builtin_amdgcn_global_load_lds((AS1 void*)(uintptr_t)(_s + (size_t)64 * IN_TOT), \
                                     (AS3 void*)(_d + 8192), 16, 0, 0);         \
} while (0)

// read the 8 A fragments of m-quadrant mq into a[]
#define RD_A(pA, mq) do {                                                       \
    _Pragma("unroll") for (int ks = 0; ks < 4; ks++) {                          \
        const int kc = ks * 2 + khalf;                                          \
        _Pragma("unroll") for (int mi = 0; mi < 2; mi++) {                      \
            const int r = (mq) * 128 + wm * 64 + mi * 32 + l32;                 \
            a[mi * 4 + ks] = *(const bf16x8*)((pA) + r * 64 + ((kc ^ (r & 7)) * 8)); \
        }                                                                       \
    }                                                                           \
} while (0)

// read the 4 B fragments of n-quadrant nq into barr[]
#define RD_B(pB, nq, barr) do {                                                 \
    _Pragma("unroll") for (int ks = 0; ks < 4; ks++) {                          \
        const int kc = ks * 2 + khalf;                                          \
        const int rb = (nq) * 128 + wn * 32 + l32;                              \
        barr[ks] = *(const bf16x8*)((pB) + rb * 64 + ((kc ^ (rb & 7)) * 8));    \
    }                                                                           \
} while (0)

// barrier -> prio -> 8 MFMA (quadrant mq x nq from a[], barr[]) -> barrier
#define MMPH(mq, nq, barr) do {                                                 \
    BAR;                                                                        \
    __builtin_amdgcn_s_setprio(1);                                              \
    _Pragma("unroll") for (int mi = 0; mi < 2; mi++)                            \
        _Pragma("unroll") for (int ks = 0; ks < 4; ks++)                        \
            acc[mq][mi][nq] = __builtin_amdgcn_mfma_f32_32x32x16_bf16(          \
                a[mi * 4 + ks], barr[ks], acc[mq][mi][nq], 0, 0, 0);            \
    __builtin_amdgcn_s_setprio(0);                                              \
    BAR;                                                                        \
} while (0)

// one K-tile = 4 phases; STGn issued in phase n, W4 waited in phase 4
#define KTILE(buf, STG1, STG2, STG3, STG4, W4) do {                             \
    const __bf16* _pA = sA + (buf) * 16384;                                     \
    const __bf16* _pB = sB + (buf) * 16384;                                     \
    RD_A(_pA, 0); RD_B(_pB, 0, b0);                                             \
    STG1;              MMPH(0, 0, b0);                                          \
    RD_B(_pB, 1, b1);                                                           \
    STG2;              MMPH(0, 1, b1);                                          \
    RD_A(_pA, 1);                                                               \
    STG3;              MMPH(1, 1, b1);                                          \
    STG4; W4;          MMPH(1, 0, b0);                                          \
} while (0)

__global__ void __launch_bounds__(512, 2) gemm_kernel(
    const __bf16* __restrict__ A,   // [BATCH][IN_TOT]
    const __bf16* __restrict__ W,   // [OUT_F][IN_TOT]
    const float*  __restrict__ bias,
    float* __restrict__ C)          // [BATCH][OUT_F]
{
    __shared__ __align__(16) __bf16 sA[2 * 256 * 64];   // 64 KiB (2 bufs)
    __shared__ __align__(16) __bf16 sB[2 * 256 * 64];   // 64 KiB

    const int tid   = threadIdx.x;
    const int bm    = blockIdx.x;    // M tile (32)
    const int bn    = blockIdx.y;    // N tile (8)
    const int wave  = tid >> 6;
    const int lane  = tid & 63;
    const int wm    = wave >> 2;     // 0..1
    const int wn    = wave & 3;      // 0..3
    const int l32   = lane & 31;
    const int khalf = lane >> 5;

    floatx16 acc[2][2][2] = {};      // [m quadrant][mi (32-row)][n quadrant]
    bf16x8 a[8];                     // A-frag cache: [mi][ks], current m-quadrant
    bf16x8 b0[4], b1[4];             // B-frag caches for n-quadrant 0 / 1

    // staging: thread t -> row = t>>3 (64 rows/load, x2 at +64), slot = t&7.
    // slot s of row r holds global chunk s ^ (r&7) => fetch chunk (t&7)^((t>>3)&7)
    const int srow   = tid >> 3;
    const int kchunk = ((tid & 7) ^ ((tid >> 3) & 7)) * 8;
    const __bf16* Ag = A + (size_t)(bm * BM + srow) * IN_TOT + kchunk;
    const __bf16* Wg = W + (size_t)(bn * BN + srow) * IN_TOT + kchunk;
    char* sAc = (char*)sA;
    char* sBc = (char*)sB;

    // prologue: tile0 fully, tile1 A-h0 + B-h1  (12 loads; wait until only
    // tile1's 4 remain outstanding)
    STAGE(Ag, sAc, 0, 0, 0);
    STAGE(Ag, sAc, 0, 0, 1);
    STAGE(Wg, sBc, 0, 0, 0);
    STAGE(Wg, sBc, 0, 0, 1);
    STAGE(Ag, sAc, 1, 1, 0);
    STAGE(Wg, sBc, 1, 1, 1);
    VMW(4);
    BAR;

#pragma unroll 1
    for (int i = 0; i < NKT / 2 - 1; ++i) {
        const int t1 = 2 * i + 1, t2 = 2 * i + 2, t3 = 2 * i + 3;
        KTILE(0, STAGE(Ag, sAc, 1, t1, 1), STAGE(Wg, sBc, 1, t1, 0),
                 STAGE(Ag, sAc, 0, t2, 0), STAGE(Wg, sBc, 0, t2, 1), VMW(4));
        KTILE(1, STAGE(Ag, sAc, 0, t2, 1), STAGE(Wg, sBc, 0, t2, 0),
                 STAGE(Ag, sAc, 1, t3, 0), STAGE(Wg, sBc, 1, t3, 1), VMW(4));
    }
    // peeled last iteration: tiles 32,33 — only tile-33 leftovers staged
    KTILE(0, STAGE(Ag, sAc, 1, NKT - 1, 1), STAGE(Wg, sBc, 1, NKT - 1, 0),
             NOPS, NOPS, VMW(0));
    KTILE(1, NOPS, NOPS, NOPS, NOPS, NOPS);

    // epilogue: C/D col = lane&31, row = (reg&3) + 8*(reg>>2) + 4*khalf  [verified]
#pragma unroll
    for (int m = 0; m < 2; m++)
#pragma unroll
    for (int mi = 0; mi < 2; mi++)
#pragma unroll
    for (int n = 0; n < 2; n++) {
        const int colg = bn * BN + n * 128 + wn * 32 + l32;
        const float bvv = bias[colg];
        const int rowb = bm * BM + m * 128 + wm * 64 + mi * 32 + 4 * khalf;
#pragma unroll
        for (int reg = 0; reg < 16; reg++) {
            const int rowg = rowb + (reg & 3) + 8 * (reg >> 2);
            C[(size_t)rowg * OUT_F + colg] = acc[m][mi][n][reg] + bvv;
        }
    }
}

// ---------------------------------------------------------------------------
// Launch
// ---------------------------------------------------------------------------
extern "C" void kernel_launch(void* const* d_in, const int* in_sizes, int n_in,
                              void* d_out, int out_size, void* d_ws, size_t ws_size,
                              hipStream_t stream) {
    const float* x      = (const float*)d_in[0];
    const float* w_vals = (const float*)d_in[1];
    const int*   w_rows = (const int*)  d_in[2];
    const int*   w_cols = (const int*)  d_in[3];
    const float* b_vals = (const float*)d_in[4];
    const int*   b_idx  = (const int*)  d_in[5];
    const float* e0v    = (const float*)d_in[6];
    const int*   e0p    = (const int*)  d_in[7];
    const float* e1v    = (const float*)d_in[8];
    const int*   e1p    = (const int*)  d_in[9];
    float* out = (float*)d_out;

    // workspace layout: Wb bf16 | bias fp32 (contiguous for single memset) | xb
    char* ws = (char*)d_ws;
    const size_t W_BF16_BYTES = (size_t)OUT_F * IN_TOT * 2;   // 8,912,896
    const size_t B_F32_BYTES  = (size_t)OUT_F * 4;            //     8,192
    __bf16* Wb  = (__bf16*)ws;
    float*  bfp = (float*)(ws + W_BF16_BYTES);
    __bf16* xb  = (__bf16*)(ws + W_BF16_BYTES + B_F32_BYTES);

    // single memset covers Wb (bf16 zero == 0x0000) + bias
    hipMemsetAsync(Wb, 0, W_BF16_BYTES + B_F32_BYTES, stream);

    prep_kernel<<<NB_BUILD + NB_SCAT, 256, 0, stream>>>(
        x, e0v, e0p, e1v, e1p, xb,
        w_vals, w_rows, w_cols, b_vals, b_idx, Wb, bfp);

    dim3 grid(BATCH / BM, OUT_F / BN);
    gemm_kernel<<<grid, 512, 0, stream>>>(xb, Wb, bfp, out);
}

// Round 5
// 218.443 us; speedup vs baseline: 1.1934x; 1.0076x over previous
//
#include <hip/hip_runtime.h>
#include <stdint.h>

#define OUT_F   2048
#define IN_BASE 2048
#define N_EMB   64
#define IN_TOT  2176   // 2048 + 128
#define NNZ_W   400000
#define NNZ_B   1024
#define BATCH   8192

typedef __bf16 bf16x8 __attribute__((ext_vector_type(8)));
typedef __bf16 bf16x4 __attribute__((ext_vector_type(4)));
typedef float  floatx16 __attribute__((ext_vector_type(16)));

#define AS1 __attribute__((address_space(1)))
#define AS3 __attribute__((address_space(3)))

// ---------------------------------------------------------------------------
// Scatter replacement: two-pass bin->accumulate (no global atomics on W).
// Pass A bins nnz by row>>3 into per-(block,bin) private segments (plain
// stores, block-private 30KB regions).  Pass B accumulates each bin's 8-row
// W slice in LDS fp32 (exact duplicate handling) and writes bf16 coalesced.
// Rationale: rounds 0-4 showed ~100us residue invariant across atomic
// flavors (CAS fp32 / global_atomic_add_f32 / pk_add_bf16) => the sink is
// the 400K random device-scope RMW pattern itself, not the opcode.
// ---------------------------------------------------------------------------
#define NSEG     391                                // ceil(400000/1024)
#define SEG_NNZ  1024                               // nnz per pass-A block
#define CAP      24                                 // entries per (block,bin)
#define NBIN     256                                // bins = row>>3
#define BIN_ELEMS (8 * IN_TOT)                      // 17408 floats per slice

#define NB_SCAT  NSEG                               // blocks 0..390
#define NB_BIAS  2                                  // blocks 391..392
#define NB_BUILD BATCH                              // blocks 393..8584

__global__ void __launch_bounds__(512) prep_kernel(
    const float* __restrict__ x,
    const float* __restrict__ e0v, const int* __restrict__ e0p,
    const float* __restrict__ e1v, const int* __restrict__ e1p,
    __bf16* __restrict__ xb,
    const float* __restrict__ wv, const int* __restrict__ wr,
    const int* __restrict__ wc,
    const float* __restrict__ bv, const int* __restrict__ bi,
    float* __restrict__ segv, unsigned short* __restrict__ segm,
    unsigned char* __restrict__ segc,
    float* __restrict__ bfp)
{
    const int tid = threadIdx.x;
    const int blk = blockIdx.x;

    if (blk < NB_SCAT) {
        // ---- pass A: bin 1024 nnz by row>>3 into private segments ----
        __shared__ unsigned int hist[NBIN];
        if (tid < NBIN) hist[tid] = 0;
        __syncthreads();
#pragma unroll
        for (int r = 0; r < 2; r++) {
            const int i = blk * SEG_NNZ + r * 512 + tid;
            if (i < NNZ_W) {
                const int row = wr[i], col = wc[i];
                const int bin = row >> 3;
                const unsigned int rank = atomicAdd(&hist[bin], 1u);
                if (rank < CAP) {   // overflow prob ~1e-9 (Poisson(4) tail)
                    const int p = (blk * NBIN + bin) * CAP + (int)rank;
                    segv[p] = wv[i];
                    segm[p] = (unsigned short)((row & 7) * IN_TOT + col);
                }
            }
        }
        __syncthreads();
        if (tid < NBIN)
            segc[blk * NBIN + tid] =
                (unsigned char)(hist[tid] < CAP ? hist[tid] : CAP);
    } else if (blk < NB_SCAT + NB_BIAS) {
        const int i = (blk - NB_SCAT) * 512 + tid;
        if (i < NNZ_B) unsafeAtomicAdd(bfp + bi[i], bv[i]);
    } else {
        // ---- build_x: one row per block, 512 threads ----
        const int b = blk - NB_SCAT - NB_BIAS;
        const float* xr = x + (size_t)b * IN_BASE;
        __bf16* xo = xb + (size_t)b * IN_TOT;

        {   // cols 0..2047: straight cast, 512 threads x 4 elems
            const float4 t = *(const float4*)(xr + tid * 4);
            bf16x4 o;
            o[0] = (__bf16)t.x; o[1] = (__bf16)t.y;
            o[2] = (__bf16)t.z; o[3] = (__bf16)t.w;
            *(bf16x4*)(xo + tid * 4) = o;
        }
        // groups 512..543 (cols 2048..2175): embeds, threads 0..31 only
        if (tid < 32) {
            const int g = 512 + tid;
            float v[4];
            if (g < 528) {                             // embed0: cols 2048..2111
                const int j = (g - 512) * 4;
#pragma unroll
                for (int t = 0; t < 4; t++) v[t] = e0v[j + t] * xr[e0p[j + t]];
            } else {                                   // embed1: cols 2112..2175
                const int j = (g - 528) * 4;
#pragma unroll
                for (int t = 0; t < 4; t++) {
                    const int p = e1p[j + t];
                    const float base = (p < IN_BASE)
                        ? xr[p]
                        : e0v[p - IN_BASE] * xr[e0p[p - IN_BASE]];
                    v[t] = e1v[j + t] * base;
                }
            }
            bf16x4 o;
            o[0] = (__bf16)v[0]; o[1] = (__bf16)v[1];
            o[2] = (__bf16)v[2]; o[3] = (__bf16)v[3];
            *(bf16x4*)(xo + g * 4) = o;
        }
    }
}

// ---------------------------------------------------------------------------
// Pass B: one block per bin.  Accumulate the bin's 8-row W slice in LDS
// (fp32, LDS float atomics), then write bf16 coalesced.  Writes EVERY slot,
// so no memset of Wb is needed.
// ---------------------------------------------------------------------------
__global__ void __launch_bounds__(512) accum_kernel(
    const float* __restrict__ segv, const unsigned short* __restrict__ segm,
    const unsigned char* __restrict__ segc,
    __bf16* __restrict__ Wb)
{
    __shared__ float Ws[BIN_ELEMS];                 // 69,632 B
    const int tid = threadIdx.x;
    const int b   = blockIdx.x;                     // bin 0..255

    for (int e = tid; e < BIN_ELEMS; e += 512) Ws[e] = 0.f;
    __syncthreads();

    for (int s = tid; s < NSEG; s += 512) {         // one segment per thread
        const int c    = segc[s * NBIN + b];
        const int base = (s * NBIN + b) * CAP;
        for (int j = 0; j < c; j++)
            atomicAdd(&Ws[segm[base + j]], segv[base + j]);
    }
    __syncthreads();

    __bf16* wo = Wb + (size_t)b * BIN_ELEMS;
    for (int e = tid; e < BIN_ELEMS / 4; e += 512) {
        bf16x4 o;
        o[0] = (__bf16)Ws[e * 4 + 0]; o[1] = (__bf16)Ws[e * 4 + 1];
        o[2] = (__bf16)Ws[e * 4 + 2]; o[3] = (__bf16)Ws[e * 4 + 3];
        *(bf16x4*)(wo + e * 4) = o;
    }
}

// ---------------------------------------------------------------------------
// Kernel 3: GEMM  C[M,N] = A[M,K] * W[N,K]^T + bias   (K-major, "NT")
// UNCHANGED from round 3/4 (verified: 80.1us, MfmaUtil 35.6%, 6.68M conflict
// cycles; model: per K-tile/block LDS drain 1536+768 cy + MFMA 2048 cy +
// barriers ~ 5661 cy measured — lockstep-serial like the m201 template).
// ---------------------------------------------------------------------------
#define BM 256
#define BN 256
#define BK 64
#define NKT (IN_TOT / BK)   // 34 K-tiles, 17 iterations of 2
static_assert(NKT % 2 == 0, "pipeline consumes K-tiles in pairs");

#define CFENCE asm volatile("" ::: "memory")
#define BAR do { CFENCE; __builtin_amdgcn_s_barrier(); CFENCE; } while (0)
#define VMW(n) asm volatile("s_waitcnt vmcnt(" #n ")" ::: "memory")
#define NOPS do {} while (0)

#define STAGE(G, SBC, buf, tile, half) do {                                     \
    const __bf16* _s = (G) + (size_t)((half) * 128) * IN_TOT + (tile) * 64;     \
    char* _d = (SBC) + (buf) * 32768 + (half) * 16384 + tid * 16;               \
    __builtin_amdgcn_global_load_lds((AS1 void*)(uintptr_t)_s,                  \
                                     (AS3 void*)_d, 16, 0, 0);                  \
    __builtin_amdgcn_global_load_lds((AS1 void*)(uintptr_t)(_s + (size_t)64 * IN_TOT), \
                                     (AS3 void*)(_d + 8192), 16, 0, 0);         \
} while (0)

#define RD_A(pA, mq) do {                                                       \
    _Pragma("unroll") for (int ks = 0; ks < 4; ks++) {                          \
        const int kc = ks * 2 + khalf;                                          \
        _Pragma("unroll") for (int mi = 0; mi < 2; mi++) {                      \
            const int r = (mq) * 128 + wm * 64 + mi * 32 + l32;                 \
            a[mi * 4 + ks] = *(const bf16x8*)((pA) + r * 64 + ((kc ^ (r & 7)) * 8)); \
        }                                                                       \
    }                                                                           \
} while (0)

#define RD_B(pB, nq, barr) do {                                                 \
    _Pragma("unroll") for (int ks = 0; ks < 4; ks++) {                          \
        const int kc = ks * 2 + khalf;                                          \
        const int rb = (nq) * 128 + wn * 32 + l32;                              \
        barr[ks] = *(const bf16x8*)((pB) + rb * 64 + ((kc ^ (rb & 7)) * 8));    \
    }                                                                           \
} while (0)

#define MMPH(mq, nq, barr) do {                                                 \
    BAR;                                                                        \
    __builtin_amdgcn_s_setprio(1);                                              \
    _Pragma("unroll") for (int mi = 0; mi < 2; mi++)                            \
        _Pragma("unroll") for (int ks = 0; ks < 4; ks++)                        \
            acc[mq][mi][nq] = __builtin_amdgcn_mfma_f32_32x32x16_bf16(          \
                a[mi * 4 + ks], barr[ks], acc[mq][mi][nq], 0, 0, 0);            \
    __builtin_amdgcn_s_setprio(0);                                              \
    BAR;                                                                        \
} while (0)

#define KTILE(buf, STG1, STG2, STG3, STG4, W4) do {                             \
    const __bf16* _pA = sA + (buf) * 16384;                                     \
    const __bf16* _pB = sB + (buf) * 16384;                                     \
    RD_A(_pA, 0); RD_B(_pB, 0, b0);                                             \
    STG1;              MMPH(0, 0, b0);                                          \
    RD_B(_pB, 1, b1);                                                           \
    STG2;              MMPH(0, 1, b1);                                          \
    RD_A(_pA, 1);                                                               \
    STG3;              MMPH(1, 1, b1);                                          \
    STG4; W4;          MMPH(1, 0, b0);                                          \
} while (0)

__global__ void __launch_bounds__(512, 2) gemm_kernel(
    const __bf16* __restrict__ A,   // [BATCH][IN_TOT]
    const __bf16* __restrict__ W,   // [OUT_F][IN_TOT]
    const float*  __restrict__ bias,
    float* __restrict__ C)          // [BATCH][OUT_F]
{
    __shared__ __align__(16) __bf16 sA[2 * 256 * 64];   // 64 KiB (2 bufs)
    __shared__ __align__(16) __bf16 sB[2 * 256 * 64];   // 64 KiB

    const int tid   = threadIdx.x;
    const int bm    = blockIdx.x;    // M tile (32)
    const int bn    = blockIdx.y;    // N tile (8)
    const int wave  = tid >> 6;
    const int lane  = tid & 63;
    const int wm    = wave >> 2;     // 0..1
    const int wn    = wave & 3;      // 0..3
    const int l32   = lane & 31;
    const int khalf = lane >> 5;

    floatx16 acc[2][2][2] = {};      // [m quadrant][mi (32-row)][n quadrant]
    bf16x8 a[8];                     // A-frag cache: [mi][ks], current m-quadrant
    bf16x8 b0[4], b1[4];             // B-frag caches for n-quadrant 0 / 1

    const int srow   = tid >> 3;
    const int kchunk = ((tid & 7) ^ ((tid >> 3) & 7)) * 8;
    const __bf16* Ag = A + (size_t)(bm * BM + srow) * IN_TOT + kchunk;
    const __bf16* Wg = W + (size_t)(bn * BN + srow) * IN_TOT + kchunk;
    char* sAc = (char*)sA;
    char* sBc = (char*)sB;

    STAGE(Ag, sAc, 0, 0, 0);
    STAGE(Ag, sAc, 0, 0, 1);
    STAGE(Wg, sBc, 0, 0, 0);
    STAGE(Wg, sBc, 0, 0, 1);
    STAGE(Ag, sAc, 1, 1, 0);
    STAGE(Wg, sBc, 1, 1, 1);
    VMW(4);
    BAR;

#pragma unroll 1
    for (int i = 0; i < NKT / 2 - 1; ++i) {
        const int t1 = 2 * i + 1, t2 = 2 * i + 2, t3 = 2 * i + 3;
        KTILE(0, STAGE(Ag, sAc, 1, t1, 1), STAGE(Wg, sBc, 1, t1, 0),
                 STAGE(Ag, sAc, 0, t2, 0), STAGE(Wg, sBc, 0, t2, 1), VMW(4));
        KTILE(1, STAGE(Ag, sAc, 0, t2, 1), STAGE(Wg, sBc, 0, t2, 0),
                 STAGE(Ag, sAc, 1, t3, 0), STAGE(Wg, sBc, 1, t3, 1), VMW(4));
    }
    KTILE(0, STAGE(Ag, sAc, 1, NKT - 1, 1), STAGE(Wg, sBc, 1, NKT - 1, 0),
             NOPS, NOPS, VMW(0));
    KTILE(1, NOPS, NOPS, NOPS, NOPS, NOPS);

    // epilogue: C/D col = lane&31, row = (reg&3) + 8*(reg>>2) + 4*khalf  [verified]
#pragma unroll
    for (int m = 0; m < 2; m++)
#pragma unroll
    for (int mi = 0; mi < 2; mi++)
#pragma unroll
    for (int n = 0; n < 2; n++) {
        const int colg = bn * BN + n * 128 + wn * 32 + l32;
        const float bvv = bias[colg];
        const int rowb = bm * BM + m * 128 + wm * 64 + mi * 32 + 4 * khalf;
#pragma unroll
        for (int reg = 0; reg < 16; reg++) {
            const int rowg = rowb + (reg & 3) + 8 * (reg >> 2);
            C[(size_t)rowg * OUT_F + colg] = acc[m][mi][n][reg] + bvv;
        }
    }
}

// ---------------------------------------------------------------------------
// Launch
// ---------------------------------------------------------------------------
extern "C" void kernel_launch(void* const* d_in, const int* in_sizes, int n_in,
                              void* d_out, int out_size, void* d_ws, size_t ws_size,
                              hipStream_t stream) {
    const float* x      = (const float*)d_in[0];
    const float* w_vals = (const float*)d_in[1];
    const int*   w_rows = (const int*)  d_in[2];
    const int*   w_cols = (const int*)  d_in[3];
    const float* b_vals = (const float*)d_in[4];
    const int*   b_idx  = (const int*)  d_in[5];
    const float* e0v    = (const float*)d_in[6];
    const int*   e0p    = (const int*)  d_in[7];
    const float* e1v    = (const float*)d_in[8];
    const int*   e1p    = (const int*)  d_in[9];
    float* out = (float*)d_out;

    // workspace: Wb | bfp | xb | segv | segm | segc   (~59.1 MB, all 16B-aligned)
    char* ws = (char*)d_ws;
    const size_t W_BF16_BYTES = (size_t)OUT_F * IN_TOT * 2;      //  8,912,896
    const size_t B_F32_BYTES  = (size_t)OUT_F * 4;               //      8,192
    const size_t XB_BYTES     = (size_t)BATCH * IN_TOT * 2;      // 35,651,584
    const size_t SEGV_BYTES   = (size_t)NSEG * NBIN * CAP * 4;   //  9,609,216
    const size_t SEGM_BYTES   = (size_t)NSEG * NBIN * CAP * 2;   //  4,804,608
    __bf16*         Wb   = (__bf16*)ws;
    float*          bfp  = (float*)(ws + W_BF16_BYTES);
    __bf16*         xb   = (__bf16*)(ws + W_BF16_BYTES + B_F32_BYTES);
    float*          segv = (float*)(ws + W_BF16_BYTES + B_F32_BYTES + XB_BYTES);
    unsigned short* segm = (unsigned short*)((char*)segv + SEGV_BYTES);
    unsigned char*  segc = (unsigned char*)((char*)segm + SEGM_BYTES);

    // only the bias accumulator needs zeroing now (8 KB)
    hipMemsetAsync(bfp, 0, B_F32_BYTES, stream);

    prep_kernel<<<NB_SCAT + NB_BIAS + NB_BUILD, 512, 0, stream>>>(
        x, e0v, e0p, e1v, e1p, xb,
        w_vals, w_rows, w_cols, b_vals, b_idx,
        segv, segm, segc, bfp);

    accum_kernel<<<NBIN, 512, 0, stream>>>(segv, segm, segc, Wb);

    dim3 grid(BATCH / BM, OUT_F / BN);
    gemm_kernel<<<grid, 512, 0, stream>>>(xb, Wb, bfp, out);
}